// Round 2
// baseline (70542.255 us; speedup 1.0000x reference)
//
#include <hip/hip_runtime.h>
#include <cstdint>
#include <cstddef>

// NeuralODE RK4, persistent kernel, 2 device-syncs per RK4 step (4094 total).
//
// Dependency insight: dR = tanh(H - A) is local per neuron, so the R-vector
// fed to each stage's matvec depends only on the matvec TWO stages back.
// Phase A: {u1,u2} = W @ {R_n, R_a}  -> locally derive R_b, R_c
// Phase B: {u3,u4} = W @ {R_b, R_c}  -> y_{n+1}, derive R_{n+1}, R_a'
//
// 128 WGs x 256 thr; WG owns 16 neurons; W rows in REGISTERS (128 VGPR/thr,
// immune to acquire-fence cache invalidation). Flag release/spin per phase.
//
// d_in: t[2048], state[4][2048], stim[2048], W[2048][2048]  (all f32)
// d_out: traj[2048][4][2048] f32
// d_ws: Rbuf[2 pairs][2 vec][2048] f32 (64KB) + flags[128] u32

#define NWG   128
#define TPB   256
#define NN    2048
#define TT    2048
#define ROWS  16
#define NP    ((TT - 1) * 2)   // 4094 phases

__global__ __launch_bounds__(TPB, 1)
void node_rk4_kernel(const float* __restrict__ tgrid,
                     const float* __restrict__ state0,
                     const float* __restrict__ stim,
                     const float* __restrict__ W,
                     float* __restrict__ out,
                     float* __restrict__ Rbuf,
                     unsigned* __restrict__ flags)
{
    const int g    = blockIdx.x;
    const int tid  = threadIdx.x;
    const int wave = tid >> 6;
    const int lane = tid & 63;
    const int n0   = g * ROWS;

    extern __shared__ float lds[];
    float* tg    = lds;          // TT floats (8KB)
    float* u_lds = lds + TT;     // 2*ROWS floats (u1[16], u2[16])

    for (int i = tid; i < TT; i += TPB) tg[i] = tgrid[i];

    // ---- W rows into registers: row 4*wave+r, float4-col lane+64k ----
    float4 w[4][8];
    {
        const float4* Wg = reinterpret_cast<const float4*>(W)
                         + (size_t)(n0 + 4 * wave) * (NN / 4);
#pragma unroll
        for (int r = 0; r < 4; ++r)
#pragma unroll
            for (int k = 0; k < 8; ++k)
                w[r][k] = Wg[(size_t)r * (NN / 4) + lane + 64 * k];
    }
    __syncthreads();   // tg ready

    // ---- owner state (threads 0..15, neuron n0+tid) ----
    float yI = 0.f, yH = 0.f, yA = 0.f, yR = 0.f, st = 0.f;
    float k1I = 0.f, k1H = 0.f, k1A = 0.f, k1R = 0.f;
    float k2I = 0.f, k2H = 0.f, k2A = 0.f, k2R = 0.f;
    float bI = 0.f, bH = 0.f, bA = 0.f, bR = 0.f;   // y_b carried A->B

    if (tid < ROWS) {
        const int i = n0 + tid;
        yI = state0[0 * NN + i];
        yH = state0[1 * NN + i];
        yA = state0[2 * NN + i];
        yR = state0[3 * NN + i];
        st = stim[i];
        out[0 * NN + i] = yI;
        out[1 * NN + i] = yH;
        out[2 * NN + i] = yA;
        out[3 * NN + i] = yR;
        // publish pair 0: vec0 = R_n, vec1 = R_a = R_n + (dt/2)*tanh(H_n - A_n)
        const float dt0 = tg[1] - tg[0];
        Rbuf[0 * NN + i] = yR;
        Rbuf[1 * NN + i] = yR + (0.5f * dt0) * tanhf(yH - yA);
    }
    __syncthreads();
    if (tid == 0)
        __hip_atomic_store(&flags[g], 1u, __ATOMIC_RELEASE, __HIP_MEMORY_SCOPE_AGENT);

    for (int p = 0; p < NP; ++p) {
        const int n = p >> 1;

        // ---- wait for all WGs to publish pair (p&1): spin, then barrier ----
        {
            const unsigned tgt = (unsigned)p + 1u;
            if (tid < NWG) {
                while (__hip_atomic_load(&flags[tid], __ATOMIC_RELAXED,
                                         __HIP_MEMORY_SCOPE_AGENT) < tgt) { }
            }
            __syncthreads();
            __threadfence();   // acquire: see other WGs' Rbuf writes
        }

        const float4* R04 = reinterpret_cast<const float4*>(Rbuf + ((p & 1) * 2 + 0) * NN);
        const float4* R14 = reinterpret_cast<const float4*>(Rbuf + ((p & 1) * 2 + 1) * NN);

        // ---- dual matvec: wave's 4 rows x {R0, R1} ----
        float a0 = 0.f, a1 = 0.f, a2 = 0.f, a3 = 0.f;
        float b0 = 0.f, b1 = 0.f, b2 = 0.f, b3 = 0.f;
#pragma unroll
        for (int k = 0; k < 8; ++k) {
            const int c = lane + 64 * k;
            const float4 ra = R04[c];
            const float4 rb = R14[c];
            a0 += w[0][k].x * ra.x + w[0][k].y * ra.y + w[0][k].z * ra.z + w[0][k].w * ra.w;
            a1 += w[1][k].x * ra.x + w[1][k].y * ra.y + w[1][k].z * ra.z + w[1][k].w * ra.w;
            a2 += w[2][k].x * ra.x + w[2][k].y * ra.y + w[2][k].z * ra.z + w[2][k].w * ra.w;
            a3 += w[3][k].x * ra.x + w[3][k].y * ra.y + w[3][k].z * ra.z + w[3][k].w * ra.w;
            b0 += w[0][k].x * rb.x + w[0][k].y * rb.y + w[0][k].z * rb.z + w[0][k].w * rb.w;
            b1 += w[1][k].x * rb.x + w[1][k].y * rb.y + w[1][k].z * rb.z + w[1][k].w * rb.w;
            b2 += w[2][k].x * rb.x + w[2][k].y * rb.y + w[2][k].z * rb.z + w[2][k].w * rb.w;
            b3 += w[3][k].x * rb.x + w[3][k].y * rb.y + w[3][k].z * rb.z + w[3][k].w * rb.w;
        }
#pragma unroll
        for (int off = 32; off > 0; off >>= 1) {
            a0 += __shfl_xor(a0, off, 64);
            a1 += __shfl_xor(a1, off, 64);
            a2 += __shfl_xor(a2, off, 64);
            a3 += __shfl_xor(a3, off, 64);
            b0 += __shfl_xor(b0, off, 64);
            b1 += __shfl_xor(b1, off, 64);
            b2 += __shfl_xor(b2, off, 64);
            b3 += __shfl_xor(b3, off, 64);
        }
        if (lane == 0) {
            u_lds[4 * wave + 0] = a0;  u_lds[4 * wave + 1] = a1;
            u_lds[4 * wave + 2] = a2;  u_lds[4 * wave + 3] = a3;
            u_lds[ROWS + 4 * wave + 0] = b0;  u_lds[ROWS + 4 * wave + 1] = b1;
            u_lds[ROWS + 4 * wave + 2] = b2;  u_lds[ROWS + 4 * wave + 3] = b3;
        }
        __syncthreads();

        // ---- owner update ----
        if (tid < ROWS) {
            const float u1 = u_lds[tid];
            const float u2 = u_lds[ROWS + tid];
            const float dt = tg[n + 1] - tg[n];
            const int   i  = n0 + tid;
            float* pub = Rbuf + (((p + 1) & 1) * 2) * NN;

            if ((p & 1) == 0) {
                // ---- phase A: k1, k2, y_b; publish R_b, R_c ----
                k1I = -yI / 5.0f + u1 + 0.1f + st;
                k1H = (-yH + 1.5f * k1I) / 10.0f;
                k1A = (-yA + 0.2f * yR) / 20.0f;
                k1R = tanhf(yH - yA);
                const float h = 0.5f * dt;
                const float aI = yI + h * k1I, aH = yH + h * k1H;
                const float aA = yA + h * k1A, aR = yR + h * k1R;
                k2I = -aI / 5.0f + u2 + 0.1f + st;
                k2H = (-aH + 1.5f * k2I) / 10.0f;
                k2A = (-aA + 0.2f * aR) / 20.0f;
                k2R = tanhf(aH - aA);
                bI = yI + h * k2I;  bH = yH + h * k2H;
                bA = yA + h * k2A;  bR = yR + h * k2R;
                const float k3R = tanhf(bH - bA);
                pub[i]      = bR;              // R_b  (stage-3 matvec input)
                pub[NN + i] = yR + dt * k3R;   // R_c  (stage-4 matvec input)
            } else {
                // ---- phase B: k3, k4, combine; publish R_{n+1}, R_a' ----
                const float k3I = -bI / 5.0f + u1 + 0.1f + st;
                const float k3H = (-bH + 1.5f * k3I) / 10.0f;
                const float k3A = (-bA + 0.2f * bR) / 20.0f;
                const float k3R = tanhf(bH - bA);
                const float cI = yI + dt * k3I, cH = yH + dt * k3H;
                const float cA = yA + dt * k3A, cR = yR + dt * k3R;
                const float k4I = -cI / 5.0f + u2 + 0.1f + st;
                const float k4H = (-cH + 1.5f * k4I) / 10.0f;
                const float k4A = (-cA + 0.2f * cR) / 20.0f;
                const float k4R = tanhf(cH - cA);
                const float h6 = dt / 6.0f;
                yI = yI + h6 * ((k1I + 2.0f * k2I) + 2.0f * k3I + k4I);
                yH = yH + h6 * ((k1H + 2.0f * k2H) + 2.0f * k3H + k4H);
                yA = yA + h6 * ((k1A + 2.0f * k2A) + 2.0f * k3A + k4A);
                yR = yR + h6 * ((k1R + 2.0f * k2R) + 2.0f * k3R + k4R);
                float* o = out + (size_t)(n + 1) * 4 * NN;
                o[0 * NN + i] = yI;
                o[1 * NN + i] = yH;
                o[2 * NN + i] = yA;
                o[3 * NN + i] = yR;
                // next step's phase-A inputs
                const float dtn = (n + 2 < TT) ? (tg[n + 2] - tg[n + 1]) : 0.0f;
                pub[i]      = yR;                                    // R_{n+1}
                pub[NN + i] = yR + (0.5f * dtn) * tanhf(yH - yA);    // R_a'
            }
        }
        __syncthreads();
        if (tid == 0)
            __hip_atomic_store(&flags[g], (unsigned)p + 2u, __ATOMIC_RELEASE,
                               __HIP_MEMORY_SCOPE_AGENT);
    }
}

extern "C" void kernel_launch(void* const* d_in, const int* in_sizes, int n_in,
                              void* d_out, int out_size, void* d_ws, size_t ws_size,
                              hipStream_t stream)
{
    const float* tgrid  = (const float*)d_in[0];
    const float* state0 = (const float*)d_in[1];
    const float* stim   = (const float*)d_in[2];
    const float* W      = (const float*)d_in[3];
    float*       out    = (float*)d_out;

    float*    Rbuf  = (float*)d_ws;                                  // 4*NN*4 = 64KB
    unsigned* flags = (unsigned*)((char*)d_ws + 4 * NN * sizeof(float));

    // ws is re-poisoned 0xAA before every timed call: flags must be zeroed.
    hipMemsetAsync(flags, 0, NWG * sizeof(unsigned), stream);

    // 84KB dynamic LDS: actual use ~8.3KB; padded so 2 WGs can't share a CU
    // (2 x 84KB > 160KB), keeping all 128 barrier participants in lockstep.
    const size_t dyn_lds = 84 * 1024;
    (void)hipFuncSetAttribute((const void*)node_rk4_kernel,
                              hipFuncAttributeMaxDynamicSharedMemorySize,
                              (int)dyn_lds);   // unconditional: same work every call

    node_rk4_kernel<<<dim3(NWG), dim3(TPB), dyn_lds, stream>>>(
        tgrid, state0, stim, W, out, Rbuf, flags);
}

// Round 3
// 34656.799 us; speedup vs baseline: 2.0355x; 2.0355x over previous
//
#include <hip/hip_runtime.h>
#include <cstdint>
#include <cstddef>

// NeuralODE RK4, persistent kernel, 2 device-syncs per RK4 step (4094 total).
//
// Round-3 changes vs round-2 (70.5 ms, 17.2us/phase, latency-bound):
//  * flags padded to 256B/WG -> no LLC line contention on release/poll
//  * 64 WGs x 512 thr (ROWS=32): half the barrier participants
//  * distributed owners: lanes 0-3 of EVERY wave update their own 4 neurons
//    straight from the butterfly result (no u_lds hop, one barrier less)
//  * per-wave s_waitcnt vmcnt(0) before barrier so tid0's release covers all
//    waves' Rbuf stores
//  * acquire-only fence on consumer side (no wbL2)
//  * out[] trajectory stores issued AFTER the flag release (off critical path)
//
// Phase A: {u1,u2} = W @ {R_n, R_a} -> derive R_b, R_c   (publish)
// Phase B: {u3,u4} = W @ {R_b, R_c} -> y_{n+1}, R_{n+1}, R_a'  (publish)
//
// d_in: t[2048], state[4][2048], stim[2048], W[2048][2048]  (all f32)
// d_out: traj[2048][4][2048] f32
// d_ws: Rbuf[2 pairs][2 vec][2048] f32 (32KB) + flags[64 * 64u32] (16KB)

#define NWG    64
#define TPB    512
#define NN     2048
#define TT     2048
#define ROWS   32            // neurons per WG (4 per wave x 8 waves)
#define NP     ((TT - 1) * 2)
#define FPAD   64            // u32 stride between flags (256B)

__global__ __launch_bounds__(TPB, 2)
void node_rk4_kernel(const float* __restrict__ tgrid,
                     const float* __restrict__ state0,
                     const float* __restrict__ stim,
                     const float* __restrict__ W,
                     float* __restrict__ out,
                     float* __restrict__ Rbuf,
                     unsigned* __restrict__ flags)
{
    const int g    = blockIdx.x;
    const int tid  = threadIdx.x;
    const int wave = tid >> 6;
    const int lane = tid & 63;
    const int n0   = g * ROWS;
    const int myrow = n0 + 4 * wave;     // first of this wave's 4 rows

    extern __shared__ float lds[];
    float* tg = lds;                     // TT floats (8KB)

    for (int i = tid; i < TT; i += TPB) tg[i] = tgrid[i];

    // ---- W rows into registers: wave's rows myrow..myrow+3, cols lane+64k ----
    float4 w[4][8];
    {
        const float4* Wg = reinterpret_cast<const float4*>(W)
                         + (size_t)myrow * (NN / 4);
#pragma unroll
        for (int r = 0; r < 4; ++r)
#pragma unroll
            for (int k = 0; k < 8; ++k)
                w[r][k] = Wg[(size_t)r * (NN / 4) + lane + 64 * k];
    }
    __syncthreads();   // tg ready

    // ---- owner state: lane r (<4) of each wave owns neuron myrow+r ----
    float yI = 0.f, yH = 0.f, yA = 0.f, yR = 0.f, st = 0.f;
    float k1I = 0.f, k1H = 0.f, k1A = 0.f, k1R = 0.f;
    float k2I = 0.f, k2H = 0.f, k2A = 0.f, k2R = 0.f;
    float bI = 0.f, bH = 0.f, bA = 0.f, bR = 0.f;

    if (lane < 4) {
        const int i = myrow + lane;
        yI = state0[0 * NN + i];
        yH = state0[1 * NN + i];
        yA = state0[2 * NN + i];
        yR = state0[3 * NN + i];
        st = stim[i];
        // publish pair 0: vec0 = R_n, vec1 = R_a = R_n + (dt0/2)*tanh(H-A)
        const float dt0 = tg[1] - tg[0];
        Rbuf[0 * NN + i] = yR;
        Rbuf[1 * NN + i] = yR + (0.5f * dt0) * tanhf(yH - yA);
    }
    asm volatile("s_waitcnt vmcnt(0)" ::: "memory");   // drain pub (per wave)
    __syncthreads();
    if (tid == 0)
        __hip_atomic_store(&flags[(size_t)g * FPAD], 1u,
                           __ATOMIC_RELEASE, __HIP_MEMORY_SCOPE_AGENT);
    if (lane < 4) {
        const int i = myrow + lane;
        out[0 * NN + i] = yI;
        out[1 * NN + i] = yH;
        out[2 * NN + i] = yA;
        out[3 * NN + i] = yR;
    }

    for (int p = 0; p < NP; ++p) {
        const int n = p >> 1;

        // ---- wait: thread t (<NWG) polls WG t's padded flag ----
        {
            const unsigned tgt = (unsigned)p + 1u;
            if (tid < NWG) {
                while (__hip_atomic_load(&flags[(size_t)tid * FPAD],
                                         __ATOMIC_RELAXED,
                                         __HIP_MEMORY_SCOPE_AGENT) < tgt) { }
            }
            __syncthreads();
            __builtin_amdgcn_fence(__ATOMIC_ACQUIRE, "agent");  // inv only
        }

        const float4* R04 = reinterpret_cast<const float4*>(Rbuf + ((p & 1) * 2 + 0) * NN);
        const float4* R14 = reinterpret_cast<const float4*>(Rbuf + ((p & 1) * 2 + 1) * NN);

        // ---- dual matvec: wave's 4 rows x {R0, R1} ----
        float a0 = 0.f, a1 = 0.f, a2 = 0.f, a3 = 0.f;
        float b0 = 0.f, b1 = 0.f, b2 = 0.f, b3 = 0.f;
#pragma unroll
        for (int k = 0; k < 8; ++k) {
            const int c = lane + 64 * k;
            const float4 ra = R04[c];
            const float4 rb = R14[c];
            a0 += w[0][k].x * ra.x + w[0][k].y * ra.y + w[0][k].z * ra.z + w[0][k].w * ra.w;
            a1 += w[1][k].x * ra.x + w[1][k].y * ra.y + w[1][k].z * ra.z + w[1][k].w * ra.w;
            a2 += w[2][k].x * ra.x + w[2][k].y * ra.y + w[2][k].z * ra.z + w[2][k].w * ra.w;
            a3 += w[3][k].x * ra.x + w[3][k].y * ra.y + w[3][k].z * ra.z + w[3][k].w * ra.w;
            b0 += w[0][k].x * rb.x + w[0][k].y * rb.y + w[0][k].z * rb.z + w[0][k].w * rb.w;
            b1 += w[1][k].x * rb.x + w[1][k].y * rb.y + w[1][k].z * rb.z + w[1][k].w * rb.w;
            b2 += w[2][k].x * rb.x + w[2][k].y * rb.y + w[2][k].z * rb.z + w[2][k].w * rb.w;
            b3 += w[3][k].x * rb.x + w[3][k].y * rb.y + w[3][k].z * rb.z + w[3][k].w * rb.w;
        }
#pragma unroll
        for (int off = 32; off > 0; off >>= 1) {
            a0 += __shfl_xor(a0, off, 64);
            a1 += __shfl_xor(a1, off, 64);
            a2 += __shfl_xor(a2, off, 64);
            a3 += __shfl_xor(a3, off, 64);
            b0 += __shfl_xor(b0, off, 64);
            b1 += __shfl_xor(b1, off, 64);
            b2 += __shfl_xor(b2, off, 64);
            b3 += __shfl_xor(b3, off, 64);
        }

        // ---- owner update: lane r (<4) uses row sums (a_r, b_r) directly ----
        bool wrote_out = false;
        float oI = 0.f, oH = 0.f, oA = 0.f, oR = 0.f;
        if (lane < 4) {
            const int   r  = lane;
            const float u1 = (r == 0) ? a0 : (r == 1) ? a1 : (r == 2) ? a2 : a3;
            const float u2 = (r == 0) ? b0 : (r == 1) ? b1 : (r == 2) ? b2 : b3;
            const float dt = tg[n + 1] - tg[n];
            const int   i  = myrow + r;
            float* pub = Rbuf + (((p + 1) & 1) * 2) * NN;

            if ((p & 1) == 0) {
                // phase A: k1, k2, y_b; publish R_b, R_c
                k1I = -yI / 5.0f + u1 + 0.1f + st;
                k1H = (-yH + 1.5f * k1I) / 10.0f;
                k1A = (-yA + 0.2f * yR) / 20.0f;
                k1R = tanhf(yH - yA);
                const float h = 0.5f * dt;
                const float aI_ = yI + h * k1I, aH_ = yH + h * k1H;
                const float aA_ = yA + h * k1A, aR_ = yR + h * k1R;
                k2I = -aI_ / 5.0f + u2 + 0.1f + st;
                k2H = (-aH_ + 1.5f * k2I) / 10.0f;
                k2A = (-aA_ + 0.2f * aR_) / 20.0f;
                k2R = tanhf(aH_ - aA_);
                bI = yI + h * k2I;  bH = yH + h * k2H;
                bA = yA + h * k2A;  bR = yR + h * k2R;
                const float k3R = tanhf(bH - bA);
                pub[i]      = bR;              // R_b
                pub[NN + i] = yR + dt * k3R;   // R_c
            } else {
                // phase B: k3, k4, combine; publish R_{n+1}, R_a'
                const float k3I = -bI / 5.0f + u1 + 0.1f + st;
                const float k3H = (-bH + 1.5f * k3I) / 10.0f;
                const float k3A = (-bA + 0.2f * bR) / 20.0f;
                const float k3R = tanhf(bH - bA);
                const float cI = yI + dt * k3I, cH = yH + dt * k3H;
                const float cA = yA + dt * k3A, cR = yR + dt * k3R;
                const float k4I = -cI / 5.0f + u2 + 0.1f + st;
                const float k4H = (-cH + 1.5f * k4I) / 10.0f;
                const float k4A = (-cA + 0.2f * cR) / 20.0f;
                const float k4R = tanhf(cH - cA);
                const float h6 = dt / 6.0f;
                yI = yI + h6 * ((k1I + 2.0f * k2I) + 2.0f * k3I + k4I);
                yH = yH + h6 * ((k1H + 2.0f * k2H) + 2.0f * k3H + k4H);
                yA = yA + h6 * ((k1A + 2.0f * k2A) + 2.0f * k3A + k4A);
                yR = yR + h6 * ((k1R + 2.0f * k2R) + 2.0f * k3R + k4R);
                const float dtn = (n + 2 < TT) ? (tg[n + 2] - tg[n + 1]) : 0.0f;
                pub[i]      = yR;                                  // R_{n+1}
                pub[NN + i] = yR + (0.5f * dtn) * tanhf(yH - yA);  // R_a'
                oI = yI; oH = yH; oA = yA; oR = yR;
                wrote_out = true;
            }
        }
        asm volatile("s_waitcnt vmcnt(0)" ::: "memory");  // drain pub (per wave)
        __syncthreads();
        if (tid == 0)
            __hip_atomic_store(&flags[(size_t)g * FPAD], (unsigned)p + 2u,
                               __ATOMIC_RELEASE, __HIP_MEMORY_SCOPE_AGENT);
        // trajectory store off the critical path (overlaps next spin)
        if (wrote_out) {
            const int i = myrow + lane;
            float* o = out + (size_t)(n + 1) * 4 * NN;
            o[0 * NN + i] = oI;
            o[1 * NN + i] = oH;
            o[2 * NN + i] = oA;
            o[3 * NN + i] = oR;
        }
    }
}

extern "C" void kernel_launch(void* const* d_in, const int* in_sizes, int n_in,
                              void* d_out, int out_size, void* d_ws, size_t ws_size,
                              hipStream_t stream)
{
    const float* tgrid  = (const float*)d_in[0];
    const float* state0 = (const float*)d_in[1];
    const float* stim   = (const float*)d_in[2];
    const float* W      = (const float*)d_in[3];
    float*       out    = (float*)d_out;

    float*    Rbuf  = (float*)d_ws;                                  // 4*NN*4 = 32KB
    unsigned* flags = (unsigned*)((char*)d_ws + 4 * NN * sizeof(float));

    // ws is re-poisoned 0xAA before every timed call: flags must start at 0.
    hipMemsetAsync(flags, 0, NWG * FPAD * sizeof(unsigned), stream);

    // LDS pad: actual use 8KB; pad so 2 WGs can't share a CU (straggler control).
    const size_t dyn_lds = 84 * 1024;
    (void)hipFuncSetAttribute((const void*)node_rk4_kernel,
                              hipFuncAttributeMaxDynamicSharedMemorySize,
                              (int)dyn_lds);   // unconditional: same work every call

    node_rk4_kernel<<<dim3(NWG), dim3(TPB), dyn_lds, stream>>>(
        tgrid, state0, stim, W, out, Rbuf, flags);
}